// Round 1
// baseline (987.332 us; speedup 1.0000x reference)
//
#include <hip/hip_runtime.h>
#include <hip/hip_bf16.h>
#include <stdint.h>

#define TS 128
#define BK 16

// ---------- edge access: handles int32 or int64 storage of edge_index ----------
__device__ __forceinline__ int edge_at(const void* ep, int isI64, long long idx) {
  if (isI64) return (int)((const long long*)ep)[idx];
  return ((const int*)ep)[idx];
}

// Detect int64 layout: if all checked odd 32-bit words are zero -> int64 (high halves).
__global__ void detect_kernel(const unsigned int* __restrict__ e, int* __restrict__ flag) {
  __shared__ int any;
  if (threadIdx.x == 0) any = 0;
  __syncthreads();
  for (int idx = 1 + 2 * (int)threadIdx.x; idx < 4096; idx += 512) {
    if (e[idx] != 0u) any = 1;
  }
  __syncthreads();
  if (threadIdx.x == 0) flag[0] = any ? 0 : 1;
}

// ---------- degree histogram (dst-based, excludes self-loop; +1 added later) ----------
__global__ void deg_kernel(const void* __restrict__ ep, const int* __restrict__ flag,
                           int* __restrict__ indeg, int E) {
  int e = blockIdx.x * blockDim.x + threadIdx.x;
  if (e >= E) return;
  int i64 = flag[0];
  int d = edge_at(ep, i64, (long long)E + e);
  atomicAdd(&indeg[d], 1);
}

__global__ void dinv_kernel(const int* __restrict__ indeg, float* __restrict__ dinv, int n) {
  int i = blockIdx.x * blockDim.x + threadIdx.x;
  if (i < n) dinv[i] = rsqrtf((float)(indeg[i] + 1));
}

// ---------- single-block prefix scan: rowptr[0]=0, rowptr[i+1]=sum(indeg[0..i]) ----------
__global__ __launch_bounds__(1024) void prefix_kernel(const int* __restrict__ indeg,
                                                      int* __restrict__ rowptr, int n) {
  __shared__ int buf[1024];
  int t = threadIdx.x;
  int carry = 0;
  if (t == 0) rowptr[0] = 0;
  for (int base = 0; base < n; base += 1024) {
    int i = base + t;
    int v = (i < n) ? indeg[i] : 0;
    buf[t] = v;
    __syncthreads();
    for (int off = 1; off < 1024; off <<= 1) {
      int add = (t >= off) ? buf[t - off] : 0;
      __syncthreads();
      buf[t] += add;
      __syncthreads();
    }
    if (i < n) rowptr[i + 1] = carry + buf[t];
    int last = buf[1023];
    __syncthreads();
    carry += last;
  }
}

// ---------- scatter edges into CSR (by dst) ----------
__global__ void scatter_kernel(const void* __restrict__ ep, const int* __restrict__ flag,
                               const int* __restrict__ rowptr, int* __restrict__ cursor,
                               int* __restrict__ colsrc, int E) {
  int e = blockIdx.x * blockDim.x + threadIdx.x;
  if (e >= E) return;
  int i64 = flag[0];
  int s = edge_at(ep, i64, (long long)e);
  int d = edge_at(ep, i64, (long long)E + e);
  int pos = atomicAdd(&cursor[d], 1);
  colsrc[rowptr[d] + pos] = s;
}

// ---------- aggregation at 256 dims: xa[i] = dinv[i]*(sum_s dinv[s]*x[s] + dinv[i]*x[i]) ----------
__global__ __launch_bounds__(256) void agg1_kernel(const float* __restrict__ x,
                                                   const float* __restrict__ dinv,
                                                   const int* __restrict__ rowptr,
                                                   const int* __restrict__ colsrc,
                                                   float* __restrict__ xa, int n) {
  int i = blockIdx.x;
  int t = threadIdx.x;  // 256 == feature dim
  float di = dinv[i];
  float acc = di * x[(size_t)i * 256 + t];
  int beg = rowptr[i], end = rowptr[i + 1];
  for (int j = beg; j < end; ++j) {
    int s = colsrc[j];
    acc += dinv[s] * x[(size_t)s * 256 + t];
  }
  xa[(size_t)i * 256 + t] = di * acc;
}

// ---------- aggregation at F dims (F<=512), adds bias: out = dinv[i]*(...) + b ----------
__global__ __launch_bounds__(256) void agg2_kernel(const float* __restrict__ g,
                                                   const float* __restrict__ dinv,
                                                   const int* __restrict__ rowptr,
                                                   const int* __restrict__ colsrc,
                                                   const float* __restrict__ bias,
                                                   float* __restrict__ out, int n, int F) {
  int i = blockIdx.x;
  int t = threadIdx.x;  // 256
  int t2 = t + 256;
  bool has2 = t2 < F;
  float di = dinv[i];
  float a0 = di * g[(size_t)i * F + t];
  float a1 = has2 ? di * g[(size_t)i * F + t2] : 0.f;
  int beg = rowptr[i], end = rowptr[i + 1];
  for (int j = beg; j < end; ++j) {
    int s = colsrc[j];
    float w = dinv[s];
    a0 += w * g[(size_t)s * F + t];
    if (has2) a1 += w * g[(size_t)s * F + t2];
  }
  out[(size_t)i * F + t] = di * a0 + bias[t];
  if (has2) out[(size_t)i * F + t2] = di * a1 + bias[t2];
}

// ---------- fp32 GEMM: C = A[MxK] @ B[KxN] (+bias)(+relu). Tile 128x128x16, 8x8/thread ----------
__global__ __launch_bounds__(256) void gemm_kernel(const float* __restrict__ A,
                                                   const float* __restrict__ B,
                                                   const float* __restrict__ bias,
                                                   float* __restrict__ C,
                                                   int M, int N, int K, int relu) {
  __shared__ __align__(16) float As[BK][TS];  // transposed: As[k][m]
  __shared__ __align__(16) float Bs[BK][TS];
  int tx = threadIdx.x & 15;
  int ty = threadIdx.x >> 4;
  int m0 = blockIdx.y * TS;
  int n0 = blockIdx.x * TS;
  float acc[8][8];
#pragma unroll
  for (int i = 0; i < 8; ++i)
#pragma unroll
    for (int j = 0; j < 8; ++j) acc[i][j] = 0.f;

  for (int k0 = 0; k0 < K; k0 += BK) {
    // Load A tile (128 rows x 16 k) as float4, store transposed into As[k][m]
#pragma unroll
    for (int i = 0; i < 2; ++i) {
      int l = (int)threadIdx.x + i * 256;  // 0..511
      int r = l >> 2;                      // row in tile 0..127
      int kq = l & 3;                      // which float4 along K
      float4 v = make_float4(0.f, 0.f, 0.f, 0.f);
      int gr = m0 + r;
      if (gr < M) v = *(const float4*)&A[(size_t)gr * K + k0 + kq * 4];
      As[kq * 4 + 0][r] = v.x;
      As[kq * 4 + 1][r] = v.y;
      As[kq * 4 + 2][r] = v.z;
      As[kq * 4 + 3][r] = v.w;
    }
    // Load B tile (16 k x 128 cols) as float4
#pragma unroll
    for (int i = 0; i < 2; ++i) {
      int l = (int)threadIdx.x + i * 256;
      int k = l >> 5;       // 0..15
      int cq = l & 31;      // which float4 along N
      int gc = n0 + cq * 4;
      float4 v = make_float4(0.f, 0.f, 0.f, 0.f);
      if (gc < N) v = *(const float4*)&B[(size_t)(k0 + k) * N + gc];
      *(float4*)&Bs[k][cq * 4] = v;
    }
    __syncthreads();
#pragma unroll
    for (int k = 0; k < BK; ++k) {
      float a[8], b[8];
      *(float4*)&a[0] = *(const float4*)&As[k][ty * 8];
      *(float4*)&a[4] = *(const float4*)&As[k][ty * 8 + 4];
      *(float4*)&b[0] = *(const float4*)&Bs[k][tx * 8];
      *(float4*)&b[4] = *(const float4*)&Bs[k][tx * 8 + 4];
#pragma unroll
      for (int i = 0; i < 8; ++i)
#pragma unroll
        for (int j = 0; j < 8; ++j) acc[i][j] += a[i] * b[j];
    }
    __syncthreads();
  }

#pragma unroll
  for (int i = 0; i < 8; ++i) {
    int gr = m0 + ty * 8 + i;
    if (gr >= M) break;
#pragma unroll
    for (int j = 0; j < 8; ++j) {
      int gc = n0 + tx * 8 + j;
      if (gc >= N) continue;
      float v = acc[i][j];
      if (bias) v += bias[gc];
      if (relu) v = fmaxf(v, 0.f);
      C[(size_t)gr * N + gc] = v;
    }
  }
}

extern "C" void kernel_launch(void* const* d_in, const int* in_sizes, int n_in,
                              void* d_out, int out_size, void* d_ws, size_t ws_size,
                              hipStream_t stream) {
  const float* x = (const float*)d_in[0];
  const void* edges = d_in[1];
  const float* W1 = (const float*)d_in[2];
  const float* b1 = (const float*)d_in[3];
  const float* W2 = (const float*)d_in[4];
  const float* b2 = (const float*)d_in[5];
  float* out = (float*)d_out;

  const int N1 = in_sizes[3];        // 1600
  const int N2 = in_sizes[5];        // 400
  const int K1 = in_sizes[2] / N1;   // 256
  const int K2 = in_sizes[4] / N2;   // 1600
  const int n = in_sizes[0] / K1;    // 20000
  const int E = in_sizes[1] / 2;     // 320000

  // ---- workspace layout ----
  char* ws = (char*)d_ws;
  size_t o = 0;
  auto take = [&](size_t bytes) {
    char* p = ws + o;
    o += (bytes + 255) & ~(size_t)255;
    return p;
  };
  int* indeg = (int*)take((size_t)n * 4);
  int* cursor = (int*)take((size_t)n * 4);
  int* flag = (int*)take(4);
  size_t zero_bytes = o;  // memset through flag
  int* rowptr = (int*)take((size_t)(n + 1) * 4);
  int* colsrc = (int*)take((size_t)E * 4);
  float* dinv = (float*)take((size_t)n * 4);
  float* xa = (float*)take((size_t)n * K1 * 4);   // 20.5 MB
  float* h = (float*)take((size_t)n * N1 * 4);    // 128 MB
  float* g = (float*)take((size_t)n * N2 * 4);    // 32 MB

  hipMemsetAsync(d_ws, 0, zero_bytes, stream);

  detect_kernel<<<1, 256, 0, stream>>>((const unsigned int*)edges, flag);
  deg_kernel<<<(E + 255) / 256, 256, 0, stream>>>(edges, flag, indeg, E);
  dinv_kernel<<<(n + 255) / 256, 256, 0, stream>>>(indeg, dinv, n);
  prefix_kernel<<<1, 1024, 0, stream>>>(indeg, rowptr, n);
  scatter_kernel<<<(E + 255) / 256, 256, 0, stream>>>(edges, flag, rowptr, cursor, colsrc, E);

  // Layer 1: aggregate at 256 dims, then GEMM (+b1, relu)
  agg1_kernel<<<n, 256, 0, stream>>>(x, dinv, rowptr, colsrc, xa, n);
  {
    dim3 grid((N1 + TS - 1) / TS, (n + TS - 1) / TS);
    gemm_kernel<<<grid, 256, 0, stream>>>(xa, W1, b1, h, n, N1, K1, 1);
  }
  // Layer 2: GEMM first (1600 -> 400, no bias), then aggregate (+b2)
  {
    dim3 grid((N2 + TS - 1) / TS, (n + TS - 1) / TS);
    gemm_kernel<<<grid, 256, 0, stream>>>(h, W2, nullptr, g, n, N2, K2, 0);
  }
  agg2_kernel<<<n, 256, 0, stream>>>(g, dinv, rowptr, colsrc, b2, out, n, N2);
}

// Round 2
// 587.243 us; speedup vs baseline: 1.6813x; 1.6813x over previous
//
#include <hip/hip_runtime.h>
#include <hip/hip_bf16.h>
#include <stdint.h>

typedef __bf16 bf16x8 __attribute__((ext_vector_type(8)));
typedef float f32x4 __attribute__((ext_vector_type(4)));

#define LDK 40  // LDS row stride (elements) for 32-wide K tiles: 80B rows -> 2-way bank alias only

// ---------- fp32 -> (hi, lo) bf16 split ----------
__device__ __forceinline__ void split_bf16(float v, unsigned short& hi, unsigned short& lo) {
  __hip_bfloat16 h = __float2bfloat16(v);
  float r = v - __bfloat162float(h);
  __hip_bfloat16 l = __float2bfloat16(r);
  hi = *(unsigned short*)&h;
  lo = *(unsigned short*)&l;
}

// ---------- edge access: handles int32 or int64 storage of edge_index ----------
__device__ __forceinline__ int edge_at(const void* ep, int isI64, long long idx) {
  if (isI64) return (int)((const long long*)ep)[idx];
  return ((const int*)ep)[idx];
}

__global__ void detect_kernel(const unsigned int* __restrict__ e, int* __restrict__ flag) {
  __shared__ int any;
  if (threadIdx.x == 0) any = 0;
  __syncthreads();
  for (int idx = 1 + 2 * (int)threadIdx.x; idx < 4096; idx += 512) {
    if (e[idx] != 0u) any = 1;
  }
  __syncthreads();
  if (threadIdx.x == 0) flag[0] = any ? 0 : 1;
}

__global__ void deg_kernel(const void* __restrict__ ep, const int* __restrict__ flag,
                           int* __restrict__ indeg, int E) {
  int e = blockIdx.x * blockDim.x + threadIdx.x;
  if (e >= E) return;
  int i64 = flag[0];
  int d = edge_at(ep, i64, (long long)E + e);
  atomicAdd(&indeg[d], 1);
}

__global__ void dinv_kernel(const int* __restrict__ indeg, float* __restrict__ dinv, int n) {
  int i = blockIdx.x * blockDim.x + threadIdx.x;
  if (i < n) dinv[i] = rsqrtf((float)(indeg[i] + 1));
}

__global__ __launch_bounds__(1024) void prefix_kernel(const int* __restrict__ indeg,
                                                      int* __restrict__ rowptr, int n) {
  __shared__ int buf[1024];
  int t = threadIdx.x;
  int carry = 0;
  if (t == 0) rowptr[0] = 0;
  for (int base = 0; base < n; base += 1024) {
    int i = base + t;
    int v = (i < n) ? indeg[i] : 0;
    buf[t] = v;
    __syncthreads();
    for (int off = 1; off < 1024; off <<= 1) {
      int add = (t >= off) ? buf[t - off] : 0;
      __syncthreads();
      buf[t] += add;
      __syncthreads();
    }
    if (i < n) rowptr[i + 1] = carry + buf[t];
    int last = buf[1023];
    __syncthreads();
    carry += last;
  }
}

__global__ void scatter_kernel(const void* __restrict__ ep, const int* __restrict__ flag,
                               const int* __restrict__ rowptr, int* __restrict__ cursor,
                               int* __restrict__ colsrc, int E) {
  int e = blockIdx.x * blockDim.x + threadIdx.x;
  if (e >= E) return;
  int i64 = flag[0];
  int s = edge_at(ep, i64, (long long)e);
  int d = edge_at(ep, i64, (long long)E + e);
  int pos = atomicAdd(&cursor[d], 1);
  colsrc[rowptr[d] + pos] = s;
}

// ---------- aggregation at 256 dims, emits bf16 hi/lo split ----------
__global__ __launch_bounds__(256) void agg1_kernel(const float* __restrict__ x,
                                                   const float* __restrict__ dinv,
                                                   const int* __restrict__ rowptr,
                                                   const int* __restrict__ colsrc,
                                                   unsigned short* __restrict__ xh,
                                                   unsigned short* __restrict__ xl, int n) {
  int i = blockIdx.x;
  int t = threadIdx.x;  // 256 == feature dim
  float di = dinv[i];
  float acc = di * x[(size_t)i * 256 + t];
  int beg = rowptr[i], end = rowptr[i + 1];
  for (int j = beg; j < end; ++j) {
    int s = colsrc[j];
    acc += dinv[s] * x[(size_t)s * 256 + t];
  }
  float v = di * acc;
  unsigned short hi, lo;
  split_bf16(v, hi, lo);
  xh[(size_t)i * 256 + t] = hi;
  xl[(size_t)i * 256 + t] = lo;
}

// ---------- aggregation at F dims (F<=512), adds bias ----------
__global__ __launch_bounds__(256) void agg2_kernel(const float* __restrict__ g,
                                                   const float* __restrict__ dinv,
                                                   const int* __restrict__ rowptr,
                                                   const int* __restrict__ colsrc,
                                                   const float* __restrict__ bias,
                                                   float* __restrict__ out, int n, int F) {
  int i = blockIdx.x;
  int t = threadIdx.x;
  int t2 = t + 256;
  bool has2 = t2 < F;
  float di = dinv[i];
  float a0 = di * g[(size_t)i * F + t];
  float a1 = has2 ? di * g[(size_t)i * F + t2] : 0.f;
  int beg = rowptr[i], end = rowptr[i + 1];
  for (int j = beg; j < end; ++j) {
    int s = colsrc[j];
    float w = dinv[s];
    a0 += w * g[(size_t)s * F + t];
    if (has2) a1 += w * g[(size_t)s * F + t2];
  }
  out[(size_t)i * F + t] = di * a0 + bias[t];
  if (has2) out[(size_t)i * F + t2] = di * a1 + bias[t2];
}

// ---------- weight split + transpose: W[K][N] -> T{h,l}[N][K] bf16 ----------
__global__ void splitT_kernel(const float* __restrict__ W, unsigned short* __restrict__ Th,
                              unsigned short* __restrict__ Tl, int K, int N) {
  int idx = blockIdx.x * 256 + threadIdx.x;
  if (idx >= K * N) return;
  int k = idx / N;
  int nn = idx - k * N;
  unsigned short hi, lo;
  split_bf16(W[idx], hi, lo);
  Th[(size_t)nn * K + k] = hi;
  Tl[(size_t)nn * K + k] = lo;
}

// ---------- split-bf16 MFMA GEMM: C = A[MxK] @ B^T[NxK]^T  (3-term split product) ----------
// Block tile 128x128, BK=32, 4 waves each computing 64x64 via 4x4 of 16x16x32 MFMAs.
__global__ __launch_bounds__(256, 2) void gemm_mfma(
    const unsigned short* __restrict__ Ah, const unsigned short* __restrict__ Al,  // [M][K]
    const unsigned short* __restrict__ Bh, const unsigned short* __restrict__ Bl,  // [N][K]
    const float* __restrict__ bias,
    float* __restrict__ Cf,                                    // fp32 out (or null)
    unsigned short* __restrict__ Ch, unsigned short* __restrict__ Cl,  // split out (or null)
    int M, int N, int K, int relu) {
  __shared__ __align__(16) unsigned short sAh[128 * LDK];
  __shared__ __align__(16) unsigned short sAl[128 * LDK];
  __shared__ __align__(16) unsigned short sBh[128 * LDK];
  __shared__ __align__(16) unsigned short sBl[128 * LDK];

  const int m0 = blockIdx.y * 128;
  const int n0 = blockIdx.x * 128;
  const int lane = threadIdx.x & 63;
  const int wave = threadIdx.x >> 6;
  const int wm = (wave & 1) * 64;
  const int wn = (wave >> 1) * 64;
  const int lrow = lane & 15;
  const int koff = (lane >> 4) * 8;

  f32x4 acc[4][4];
#pragma unroll
  for (int i = 0; i < 4; ++i)
#pragma unroll
    for (int j = 0; j < 4; ++j) acc[i][j] = (f32x4)(0.f);

  for (int k0 = 0; k0 < K; k0 += 32) {
    // stage 4 tiles: each 128 rows x 32 k of bf16 (8KB). 512 16B-chunks, 2/thread.
#pragma unroll
    for (int i = 0; i < 2; ++i) {
      int c = (int)threadIdx.x + i * 256;
      int row = c >> 2;
      int kq = (c & 3) * 8;
      size_t goff;
      uint4 v;
      int gr = m0 + row;
      v = make_uint4(0, 0, 0, 0);
      if (gr < M) {
        goff = (size_t)gr * K + k0 + kq;
        v = *(const uint4*)&Ah[goff];
      }
      *(uint4*)&sAh[row * LDK + kq] = v;
      v = make_uint4(0, 0, 0, 0);
      if (gr < M) v = *(const uint4*)&Al[(size_t)gr * K + k0 + kq];
      *(uint4*)&sAl[row * LDK + kq] = v;
      int gn = n0 + row;
      v = make_uint4(0, 0, 0, 0);
      if (gn < N) v = *(const uint4*)&Bh[(size_t)gn * K + k0 + kq];
      *(uint4*)&sBh[row * LDK + kq] = v;
      v = make_uint4(0, 0, 0, 0);
      if (gn < N) v = *(const uint4*)&Bl[(size_t)gn * K + k0 + kq];
      *(uint4*)&sBl[row * LDK + kq] = v;
    }
    __syncthreads();

    bf16x8 ah[4], al[4], bh[4], bl[4];
#pragma unroll
    for (int i = 0; i < 4; ++i) {
      ah[i] = *(const bf16x8*)&sAh[(wm + i * 16 + lrow) * LDK + koff];
      al[i] = *(const bf16x8*)&sAl[(wm + i * 16 + lrow) * LDK + koff];
      bh[i] = *(const bf16x8*)&sBh[(wn + i * 16 + lrow) * LDK + koff];
      bl[i] = *(const bf16x8*)&sBl[(wn + i * 16 + lrow) * LDK + koff];
    }
#pragma unroll
    for (int i = 0; i < 4; ++i)
#pragma unroll
      for (int j = 0; j < 4; ++j) {
        acc[i][j] = __builtin_amdgcn_mfma_f32_16x16x32_bf16(ah[i], bh[j], acc[i][j], 0, 0, 0);
        acc[i][j] = __builtin_amdgcn_mfma_f32_16x16x32_bf16(ah[i], bl[j], acc[i][j], 0, 0, 0);
        acc[i][j] = __builtin_amdgcn_mfma_f32_16x16x32_bf16(al[i], bh[j], acc[i][j], 0, 0, 0);
      }
    __syncthreads();
  }

  // epilogue: C row = (lane>>4)*4 + r, col = lane&15  [m89 mapping]
  const int crow = (lane >> 4) * 4;
  const int ccol = lane & 15;
#pragma unroll
  for (int j = 0; j < 4; ++j) {
    int gcol = n0 + wn + j * 16 + ccol;
    if (gcol >= N) continue;
    float bv = bias ? bias[gcol] : 0.f;
#pragma unroll
    for (int i = 0; i < 4; ++i) {
#pragma unroll
      for (int r = 0; r < 4; ++r) {
        int grow = m0 + wm + i * 16 + crow + r;
        if (grow >= M) continue;
        float v = acc[i][j][r] + bv;
        if (relu) v = fmaxf(v, 0.f);
        if (Cf) {
          Cf[(size_t)grow * N + gcol] = v;
        } else {
          unsigned short hi, lo;
          split_bf16(v, hi, lo);
          Ch[(size_t)grow * N + gcol] = hi;
          Cl[(size_t)grow * N + gcol] = lo;
        }
      }
    }
  }
}

extern "C" void kernel_launch(void* const* d_in, const int* in_sizes, int n_in,
                              void* d_out, int out_size, void* d_ws, size_t ws_size,
                              hipStream_t stream) {
  const float* x = (const float*)d_in[0];
  const void* edges = d_in[1];
  const float* W1 = (const float*)d_in[2];
  const float* b1 = (const float*)d_in[3];
  const float* W2 = (const float*)d_in[4];
  const float* b2 = (const float*)d_in[5];
  float* out = (float*)d_out;

  const int N1 = in_sizes[3];       // 1600
  const int N2 = in_sizes[5];       // 400
  const int K1 = in_sizes[2] / N1;  // 256
  const int K2 = in_sizes[4] / N2;  // 1600
  const int n = in_sizes[0] / K1;   // 20000
  const int E = in_sizes[1] / 2;    // 320000

  // ---- workspace layout ----
  char* ws = (char*)d_ws;
  size_t o = 0;
  auto take = [&](size_t bytes) {
    char* p = ws + o;
    o += (bytes + 255) & ~(size_t)255;
    return p;
  };
  int* indeg = (int*)take((size_t)n * 4);
  int* cursor = (int*)take((size_t)n * 4);
  int* flag = (int*)take(4);
  size_t zero_bytes = o;  // memset through flag
  int* rowptr = (int*)take((size_t)(n + 1) * 4);
  int* colsrc = (int*)take((size_t)E * 4);
  float* dinv = (float*)take((size_t)n * 4);
  unsigned short* xh = (unsigned short*)take((size_t)n * K1 * 2);
  unsigned short* xl = (unsigned short*)take((size_t)n * K1 * 2);
  unsigned short* w1h = (unsigned short*)take((size_t)K1 * N1 * 2);
  unsigned short* w1l = (unsigned short*)take((size_t)K1 * N1 * 2);
  unsigned short* w2h = (unsigned short*)take((size_t)K2 * N2 * 2);
  unsigned short* w2l = (unsigned short*)take((size_t)K2 * N2 * 2);
  unsigned short* hh = (unsigned short*)take((size_t)n * N1 * 2);  // 64 MB
  unsigned short* hl = (unsigned short*)take((size_t)n * N1 * 2);  // 64 MB
  float* g = (float*)take((size_t)n * N2 * 4);                     // 32 MB

  hipMemsetAsync(d_ws, 0, zero_bytes, stream);

  detect_kernel<<<1, 256, 0, stream>>>((const unsigned int*)edges, flag);
  deg_kernel<<<(E + 255) / 256, 256, 0, stream>>>(edges, flag, indeg, E);
  dinv_kernel<<<(n + 255) / 256, 256, 0, stream>>>(indeg, dinv, n);
  prefix_kernel<<<1, 1024, 0, stream>>>(indeg, rowptr, n);
  scatter_kernel<<<(E + 255) / 256, 256, 0, stream>>>(edges, flag, rowptr, cursor, colsrc, E);

  // weight splits (+transpose to [N][K])
  splitT_kernel<<<(K1 * N1 + 255) / 256, 256, 0, stream>>>(W1, w1h, w1l, K1, N1);
  splitT_kernel<<<(K2 * N2 + 255) / 256, 256, 0, stream>>>(W2, w2h, w2l, K2, N2);

  // Layer 1: aggregate at 256 dims (split out), then MFMA GEMM (+b1, relu, split out)
  agg1_kernel<<<n, 256, 0, stream>>>(x, dinv, rowptr, colsrc, xh, xl, n);
  {
    dim3 grid((N1 + 127) / 128, (n + 127) / 128);
    gemm_mfma<<<grid, 256, 0, stream>>>(xh, xl, w1h, w1l, b1, nullptr, hh, hl, n, N1, K1, 1);
  }
  // Layer 2: MFMA GEMM (fp32 out), then aggregate (+b2)
  {
    dim3 grid((N2 + 127) / 128, (n + 127) / 128);
    gemm_mfma<<<grid, 256, 0, stream>>>(hh, hl, w2h, w2l, nullptr, g, nullptr, nullptr, n, N2, K2, 0);
  }
  agg2_kernel<<<n, 256, 0, stream>>>(g, dinv, rowptr, colsrc, b2, out, n, N2);
}

// Round 3
// 373.087 us; speedup vs baseline: 2.6464x; 1.5740x over previous
//
#include <hip/hip_runtime.h>
#include <hip/hip_bf16.h>
#include <stdint.h>

typedef _Float16 f16;
typedef _Float16 f16x8 __attribute__((ext_vector_type(8)));
typedef _Float16 f16x2 __attribute__((ext_vector_type(2)));
typedef float f32x4 __attribute__((ext_vector_type(4)));

#define LDK 40  // LDS row stride (fp16 elems): 80B rows, 2-way bank alias only (free per m136)

// ---------- edge access: handles int32 or int64 storage of edge_index ----------
__device__ __forceinline__ int edge_at(const void* ep, int isI64, long long idx) {
  if (isI64) return (int)((const long long*)ep)[idx];
  return ((const int*)ep)[idx];
}

__global__ void detect_kernel(const unsigned int* __restrict__ e, int* __restrict__ flag) {
  __shared__ int any;
  if (threadIdx.x == 0) any = 0;
  __syncthreads();
  for (int idx = 1 + 2 * (int)threadIdx.x; idx < 4096; idx += 512) {
    if (e[idx] != 0u) any = 1;
  }
  __syncthreads();
  if (threadIdx.x == 0) flag[0] = any ? 0 : 1;
}

__global__ void deg_kernel(const void* __restrict__ ep, const int* __restrict__ flag,
                           int* __restrict__ indeg, int E) {
  int e = blockIdx.x * blockDim.x + threadIdx.x;
  if (e >= E) return;
  int i64 = flag[0];
  int d = edge_at(ep, i64, (long long)E + e);
  atomicAdd(&indeg[d], 1);
}

__global__ void dinv_kernel(const int* __restrict__ indeg, float* __restrict__ dinv, int n) {
  int i = blockIdx.x * blockDim.x + threadIdx.x;
  if (i < n) dinv[i] = rsqrtf((float)(indeg[i] + 1));
}

// ---------- prefix scan: wave-shuffle based, 3 barriers per 1024-chunk ----------
__global__ __launch_bounds__(1024) void prefix_kernel(const int* __restrict__ indeg,
                                                      int* __restrict__ rowptr, int n) {
  __shared__ int wsum[16];
  int t = threadIdx.x;
  int lane = t & 63;
  int w = t >> 6;
  int carry = 0;
  if (t == 0) rowptr[0] = 0;
  for (int base = 0; base < n; base += 1024) {
    int i = base + t;
    int v = (i < n) ? indeg[i] : 0;
    int sv = v;
#pragma unroll
    for (int off = 1; off < 64; off <<= 1) {
      int u = __shfl_up(sv, off, 64);
      if (lane >= off) sv += u;
    }
    if (lane == 63) wsum[w] = sv;
    __syncthreads();
    if (w == 0 && lane < 16) {
      int ws = wsum[lane];
#pragma unroll
      for (int off = 1; off < 16; off <<= 1) {
        int u = __shfl_up(ws, off, 64);
        if (lane >= off) ws += u;
      }
      wsum[lane] = ws;
    }
    __syncthreads();
    int woff = (w > 0) ? wsum[w - 1] : 0;
    if (i < n) rowptr[i + 1] = carry + woff + sv;
    carry += wsum[15];
    __syncthreads();
  }
}

__global__ void scatter_kernel(const void* __restrict__ ep, const int* __restrict__ flag,
                               const int* __restrict__ rowptr, int* __restrict__ cursor,
                               int* __restrict__ colsrc, int E) {
  int e = blockIdx.x * blockDim.x + threadIdx.x;
  if (e >= E) return;
  int i64 = flag[0];
  int s = edge_at(ep, i64, (long long)e);
  int d = edge_at(ep, i64, (long long)E + e);
  int pos = atomicAdd(&cursor[d], 1);
  colsrc[rowptr[d] + pos] = s;
}

// ---------- aggregation at 256 dims, fp32 math, fp16 out, 4-way unrolled ----------
__global__ __launch_bounds__(256) void agg1_kernel(const float* __restrict__ x,
                                                   const float* __restrict__ dinv,
                                                   const int* __restrict__ rowptr,
                                                   const int* __restrict__ colsrc,
                                                   f16* __restrict__ xa, int n) {
  int i = blockIdx.x;
  int t = threadIdx.x;  // 256 == feature dim
  float di = dinv[i];
  float a0 = di * x[(size_t)i * 256 + t];
  float a1 = 0.f;
  int beg = rowptr[i], end = rowptr[i + 1];
  int j = beg;
  for (; j + 3 < end; j += 4) {
    int s0 = colsrc[j], s1 = colsrc[j + 1], s2 = colsrc[j + 2], s3 = colsrc[j + 3];
    float w0 = dinv[s0], w1 = dinv[s1], w2 = dinv[s2], w3 = dinv[s3];
    float v0 = x[(size_t)s0 * 256 + t], v1 = x[(size_t)s1 * 256 + t];
    float v2 = x[(size_t)s2 * 256 + t], v3 = x[(size_t)s3 * 256 + t];
    a0 += w0 * v0 + w2 * v2;
    a1 += w1 * v1 + w3 * v3;
  }
  for (; j < end; ++j) {
    int s = colsrc[j];
    a0 += dinv[s] * x[(size_t)s * 256 + t];
  }
  xa[(size_t)i * 256 + t] = (f16)(di * (a0 + a1));
}

// ---------- aggregation over fp16 g at F dims (pairs), adds bias, fp32 out ----------
__global__ __launch_bounds__(256) void agg2_kernel(const f16* __restrict__ g,
                                                   const float* __restrict__ dinv,
                                                   const int* __restrict__ rowptr,
                                                   const int* __restrict__ colsrc,
                                                   const float* __restrict__ bias,
                                                   float* __restrict__ out, int n, int F) {
  int i = blockIdx.x;
  int t = threadIdx.x;
  int pairs = F >> 1;
  if (t >= pairs) return;
  float di = dinv[i];
  f16x2 self = *(const f16x2*)&g[(size_t)i * F + 2 * t];
  float a0 = di * (float)self[0], b0 = di * (float)self[1];
  float a1 = 0.f, b1 = 0.f;
  int beg = rowptr[i], end = rowptr[i + 1];
  int j = beg;
  for (; j + 3 < end; j += 4) {
    int s0 = colsrc[j], s1 = colsrc[j + 1], s2 = colsrc[j + 2], s3 = colsrc[j + 3];
    float w0 = dinv[s0], w1 = dinv[s1], w2 = dinv[s2], w3 = dinv[s3];
    f16x2 v0 = *(const f16x2*)&g[(size_t)s0 * F + 2 * t];
    f16x2 v1 = *(const f16x2*)&g[(size_t)s1 * F + 2 * t];
    f16x2 v2 = *(const f16x2*)&g[(size_t)s2 * F + 2 * t];
    f16x2 v3 = *(const f16x2*)&g[(size_t)s3 * F + 2 * t];
    a0 += w0 * (float)v0[0] + w2 * (float)v2[0];
    b0 += w0 * (float)v0[1] + w2 * (float)v2[1];
    a1 += w1 * (float)v1[0] + w3 * (float)v3[0];
    b1 += w1 * (float)v1[1] + w3 * (float)v3[1];
  }
  for (; j < end; ++j) {
    int s = colsrc[j];
    float w = dinv[s];
    f16x2 v = *(const f16x2*)&g[(size_t)s * F + 2 * t];
    a0 += w * (float)v[0];
    b0 += w * (float)v[1];
  }
  float2 o;
  o.x = di * (a0 + a1) + bias[2 * t];
  o.y = di * (b0 + b1) + bias[2 * t + 1];
  *(float2*)&out[(size_t)i * F + 2 * t] = o;
}

// ---------- weight cast + transpose: W[K][N] -> Wt[N][K] fp16 ----------
__global__ void castT_kernel(const float* __restrict__ W, f16* __restrict__ Wt, int K, int N) {
  int idx = blockIdx.x * 256 + threadIdx.x;
  if (idx >= K * N) return;
  int k = idx / N;
  int nn = idx - k * N;
  Wt[(size_t)nn * K + k] = (f16)W[idx];
}

// ---------- fp16 MFMA GEMM: C = A[MxK] @ B[NxK]^T, fp16 out ----------
// Block tile 128x128, BK=32, 4 waves each 64x64 via 4x4 of 16x16x32 MFMAs.
__global__ __launch_bounds__(256) void gemm_f16(
    const f16* __restrict__ A,  // [M][K]
    const f16* __restrict__ B,  // [N][K]
    const float* __restrict__ bias,
    f16* __restrict__ C,        // [M][N]
    int M, int N, int K, int relu, int swz) {
  __shared__ __align__(16) f16 sA[128 * LDK];
  __shared__ __align__(16) f16 sB[128 * LDK];

  int mt, nt;
  if (swz && gridDim.x == 4) {
    // map the 4 n-tiles of one m-tile onto the same XCD (round-robin assumption)
    int idf = blockIdx.y * gridDim.x + blockIdx.x;
    int nb = gridDim.x * gridDim.y;
    int full = (nb / 32) * 32;
    if (idf < full) {
      int xcd = idf & 7;
      int slot = idf >> 3;
      nt = slot & 3;
      mt = xcd + 8 * (slot >> 2);
    } else {
      int r = idf - full;
      nt = r & 3;
      mt = (full >> 2) + (r >> 2);
    }
  } else {
    nt = blockIdx.x;
    mt = blockIdx.y;
  }
  const int m0 = mt * 128;
  const int n0 = nt * 128;
  const int lane = threadIdx.x & 63;
  const int wave = threadIdx.x >> 6;
  const int wm = (wave & 1) * 64;
  const int wn = (wave >> 1) * 64;
  const int lrow = lane & 15;
  const int koff = (lane >> 4) * 8;

  f32x4 acc[4][4];
#pragma unroll
  for (int i = 0; i < 4; ++i)
#pragma unroll
    for (int j = 0; j < 4; ++j) acc[i][j] = (f32x4)(0.f);

  for (int k0 = 0; k0 < K; k0 += 32) {
    // stage 2 tiles: each 128 rows x 32 k of fp16 (8KB) = 512 16B-chunks, 2/thread.
#pragma unroll
    for (int i = 0; i < 2; ++i) {
      int c = (int)threadIdx.x + i * 256;
      int row = c >> 2;
      int kq = (c & 3) * 8;
      uint4 v = make_uint4(0, 0, 0, 0);
      int gr = m0 + row;
      if (gr < M) v = *(const uint4*)&A[(size_t)gr * K + k0 + kq];
      *(uint4*)&sA[row * LDK + kq] = v;
      v = make_uint4(0, 0, 0, 0);
      int gn = n0 + row;
      if (gn < N) v = *(const uint4*)&B[(size_t)gn * K + k0 + kq];
      *(uint4*)&sB[row * LDK + kq] = v;
    }
    __syncthreads();

    f16x8 af[4], bf[4];
#pragma unroll
    for (int i = 0; i < 4; ++i) {
      af[i] = *(const f16x8*)&sA[(wm + i * 16 + lrow) * LDK + koff];
      bf[i] = *(const f16x8*)&sB[(wn + i * 16 + lrow) * LDK + koff];
    }
#pragma unroll
    for (int i = 0; i < 4; ++i)
#pragma unroll
      for (int j = 0; j < 4; ++j)
        acc[i][j] = __builtin_amdgcn_mfma_f32_16x16x32_f16(af[i], bf[j], acc[i][j], 0, 0, 0);
    __syncthreads();
  }

  // epilogue: C row = (lane>>4)*4 + r, col = lane&15  [m89 mapping]
  const int crow = (lane >> 4) * 4;
  const int ccol = lane & 15;
#pragma unroll
  for (int j = 0; j < 4; ++j) {
    int gcol = n0 + wn + j * 16 + ccol;
    if (gcol >= N) continue;
    float bv = bias ? bias[gcol] : 0.f;
#pragma unroll
    for (int i = 0; i < 4; ++i) {
#pragma unroll
      for (int r = 0; r < 4; ++r) {
        int grow = m0 + wm + i * 16 + crow + r;
        if (grow >= M) continue;
        float v = acc[i][j][r] + bv;
        if (relu) v = fmaxf(v, 0.f);
        C[(size_t)grow * N + gcol] = (f16)v;
      }
    }
  }
}

extern "C" void kernel_launch(void* const* d_in, const int* in_sizes, int n_in,
                              void* d_out, int out_size, void* d_ws, size_t ws_size,
                              hipStream_t stream) {
  const float* x = (const float*)d_in[0];
  const void* edges = d_in[1];
  const float* W1 = (const float*)d_in[2];
  const float* b1 = (const float*)d_in[3];
  const float* W2 = (const float*)d_in[4];
  const float* b2 = (const float*)d_in[5];
  float* out = (float*)d_out;

  const int N1 = in_sizes[3];       // 1600
  const int N2 = in_sizes[5];       // 400
  const int K1 = in_sizes[2] / N1;  // 256
  const int K2 = in_sizes[4] / N2;  // 1600
  const int n = in_sizes[0] / K1;   // 20000
  const int E = in_sizes[1] / 2;    // 320000

  // ---- workspace layout ----
  char* ws = (char*)d_ws;
  size_t o = 0;
  auto take = [&](size_t bytes) {
    char* p = ws + o;
    o += (bytes + 255) & ~(size_t)255;
    return p;
  };
  int* indeg = (int*)take((size_t)n * 4);
  int* cursor = (int*)take((size_t)n * 4);
  int* flag = (int*)take(4);
  size_t zero_bytes = o;  // memset through flag
  int* rowptr = (int*)take((size_t)(n + 1) * 4);
  int* colsrc = (int*)take((size_t)E * 4);
  float* dinv = (float*)take((size_t)n * 4);
  f16* xa = (f16*)take((size_t)n * K1 * 2);       // 10 MB
  f16* w1t = (f16*)take((size_t)K1 * N1 * 2);     // 0.8 MB
  f16* w2t = (f16*)take((size_t)K2 * N2 * 2);     // 1.3 MB
  f16* h = (f16*)take((size_t)n * N1 * 2);        // 64 MB
  f16* g = (f16*)take((size_t)n * N2 * 2);        // 16 MB

  hipMemsetAsync(d_ws, 0, zero_bytes, stream);

  detect_kernel<<<1, 256, 0, stream>>>((const unsigned int*)edges, flag);
  deg_kernel<<<(E + 255) / 256, 256, 0, stream>>>(edges, flag, indeg, E);
  dinv_kernel<<<(n + 255) / 256, 256, 0, stream>>>(indeg, dinv, n);
  prefix_kernel<<<1, 1024, 0, stream>>>(indeg, rowptr, n);
  scatter_kernel<<<(E + 255) / 256, 256, 0, stream>>>(edges, flag, rowptr, cursor, colsrc, E);

  // weight casts (+transpose to [N][K])
  castT_kernel<<<(K1 * N1 + 255) / 256, 256, 0, stream>>>(W1, w1t, K1, N1);
  castT_kernel<<<(K2 * N2 + 255) / 256, 256, 0, stream>>>(W2, w2t, K2, N2);

  // Layer 1: aggregate at 256 dims (fp16 out), then MFMA GEMM (+b1, relu, fp16 out)
  agg1_kernel<<<n, 256, 0, stream>>>(x, dinv, rowptr, colsrc, xa, n);
  {
    dim3 grid((N1 + 127) / 128, (n + 127) / 128);
    gemm_f16<<<grid, 256, 0, stream>>>(xa, w1t, b1, h, n, N1, K1, 1, 0);
  }
  // Layer 2: MFMA GEMM (fp16 out), then aggregate (+b2, fp32 out)
  {
    dim3 grid((N2 + 127) / 128, (n + 127) / 128);
    gemm_f16<<<grid, 256, 0, stream>>>(h, w2t, nullptr, g, n, N2, K2, 0, 1);
  }
  agg2_kernel<<<n, 256, 0, stream>>>(g, dinv, rowptr, colsrc, b2, out, n, N2);
}